// Round 7
// baseline (419.118 us; speedup 1.0000x reference)
//
#include <hip/hip_runtime.h>
#include <math.h>

#define N_NODES 50000
#define N_PAD   50048              // rows padded to multiple of 64
#define N_EDGES 1600000
#define DIM     128
#define RCUT    5.0f
#define NG4     (N_PAD / 4)        // 12512 groups of 4 nodes
#define NB_PRE  256
#define CH_PRE  (N_EDGES / NB_PRE) // 6250 edges per preprocessing block

typedef __attribute__((ext_vector_type(8))) __bf16 bf16x8;
typedef __attribute__((ext_vector_type(4))) float  f32x4;

// ---------------- bf16 helpers ----------------
__device__ __forceinline__ float bf_lo(unsigned int u) { return __uint_as_float(u << 16); }
__device__ __forceinline__ float bf_hi(unsigned int u) { return __uint_as_float(u & 0xffff0000u); }
__device__ __forceinline__ unsigned short f2bf(float x) {
    unsigned int u = __float_as_uint(x);
    u += 0x7fffu + ((u >> 16) & 1u);   // round-to-nearest-even
    return (unsigned short)(u >> 16);
}

// ---------------- fused: v->bf16 convert + W->MFMA-B fragments ----------------
// blocks [0,6250): convert 1.6M float4 groups; blocks [6250,6258): wprep 2048 frags
__global__ __launch_bounds__(256) void prep_kernel(
        const float* __restrict__ v, unsigned short* __restrict__ vb,
        const float* __restrict__ Aw, uint4* __restrict__ wfrag) {
    int b = blockIdx.x;
    if (b < 6250) {
        int i = b * 256 + threadIdx.x;           // exactly N_NODES*DIM/4 = 1.6M
        float4 x = ((const float4*)v)[i];
        uint2 o;
        o.x = (unsigned)f2bf(x.x) | ((unsigned)f2bf(x.y) << 16);
        o.y = (unsigned)f2bf(x.z) | ((unsigned)f2bf(x.w) << 16);
        ((uint2*)vb)[i] = o;
    } else {
        int t = (b - 6250) * 256 + threadIdx.x;  // 0..2047
        int lane = t & 63, nt = (t >> 6) & 7, kk = t >> 9;
        int n  = nt * 16 + (lane & 15);
        int k0 = kk * 32 + (lane >> 4) * 8;
        unsigned short h[8];
        #pragma unroll
        for (int i = 0; i < 8; ++i) h[i] = f2bf(Aw[n * DIM + k0 + i]);
        uint4 o;
        o.x = h[0] | ((unsigned)h[1] << 16); o.y = h[2] | ((unsigned)h[3] << 16);
        o.z = h[4] | ((unsigned)h[5] << 16); o.w = h[6] | ((unsigned)h[7] << 16);
        wfrag[t] = o;
    }
}

// ---------------- per-block 4-node-group histogram (LDS only) ----------------
__global__ __launch_bounds__(256) void countp_kernel(const int* __restrict__ dst,
                                                     int* __restrict__ partial) {
    __shared__ int h[NG4];                       // 50,048 B
    int b = blockIdx.x, tid = threadIdx.x;
    for (int g = tid; g < NG4; g += 256) h[g] = 0;
    __syncthreads();
    int beg = b * CH_PRE, end = beg + CH_PRE;
    for (int i = beg + tid; i < end; i += 256)
        atomicAdd(&h[dst[i] >> 2], 1);           // LDS atomic
    __syncthreads();
    for (int g = tid; g < NG4; g += 256) partial[b * NG4 + g] = h[g];
}

// ---------------- group totals (coalesced over [b][g] layout) ----------------
__global__ __launch_bounds__(256) void ktot_kernel(const int* __restrict__ partial,
                                                   int* __restrict__ gtot) {
    int g = blockIdx.x * 256 + threadIdx.x;
    if (g >= NG4) return;
    int s = 0;
    for (int b = 0; b < NB_PRE; ++b) s += partial[b * NG4 + g];
    gtot[g] = s;
}

// ---------------- exclusive scan over 12512 group totals ----------------
__global__ __launch_bounds__(256) void kscan_kernel(const int* __restrict__ gtot,
                                                    int* __restrict__ goff) {
    __shared__ int part[256];
    int tid = threadIdx.x;
    const int CH = (NG4 + 255) / 256;            // 49
    int beg = tid * CH;
    int end = beg + CH; if (end > NG4) end = NG4;
    int s = 0;
    for (int i = beg; i < end; ++i) s += gtot[i];
    part[tid] = s; __syncthreads();
    for (int d = 1; d < 256; d <<= 1) {
        int val = (tid >= d) ? part[tid - d] : 0;
        __syncthreads(); part[tid] += val; __syncthreads();
    }
    int run = (tid == 0) ? 0 : part[tid - 1];
    for (int i = beg; i < end; ++i) { goff[i] = run; run += gtot[i]; }
    if (tid == 0) goff[NG4] = N_EDGES;
}

// ---------------- per-(block,group) bases (coalesced) ----------------
__global__ __launch_bounds__(256) void kbase_kernel(const int* __restrict__ partial,
                                                    const int* __restrict__ goff,
                                                    int* __restrict__ pbase) {
    int g = blockIdx.x * 256 + threadIdx.x;
    if (g >= NG4) return;
    int run = goff[g];
    for (int b = 0; b < NB_PRE; ++b) {
        pbase[b * NG4 + g] = run;
        run += partial[b * NG4 + g];
    }
}

// ---------------- reorder straight into group-CSR with node tags ----------
// meta[slot] = { src*256 | (dst&3)<<24, bitcast(f) }
__global__ __launch_bounds__(256) void reorder_kernel(
        const float* __restrict__ e,
        const int*   __restrict__ src,
        const int*   __restrict__ dst,
        const float* __restrict__ rs,
        const float* __restrict__ sigma,
        const int*   __restrict__ pbase,
        int2* __restrict__ meta) {
    __shared__ int cnt[NG4];                     // 50,048 B
    int b = blockIdx.x, tid = threadIdx.x;
    for (int g = tid; g < NG4; g += 256) cnt[g] = 0;
    __syncthreads();
    float rsv = rs[0], sg = sigma[0];
    const int* pb = pbase + b * NG4;             // 50 KB row, L2-resident
    int beg = b * CH_PRE, end = beg + CH_PRE;
    for (int i = beg + tid; i < end; i += 256) {
        float r  = e[i];
        float d  = r - rsv;
        float gauss = expf(-(d * d) / (sg * sg));
        float cut   = 0.5f * cosf(r * (float)(M_PI / (double)RCUT));
        cut = (r < RCUT) ? cut : 0.0f;
        float fe = gauss * cut;
        int dn = dst[i];
        int g  = dn >> 2;
        int lr = atomicAdd(&cnt[g], 1);          // LDS atomic
        int slot = pb[g] + lr;
        meta[slot] = make_int2(src[i] * (DIM * 2) | ((dn & 3) << 24),
                               __float_as_int(fe));
    }
}

// ---------------- fused layer: gather(4-node groups) + MFMA GEMM + relu ----
// Block = 4 waves. Wave wv gathers group g = blk*4+wv (4 nodes, reg acc
// selected by uniform tag). Block's 16 rows -> LDS -> 16x128 MFMA tile.
#define GACC(mx, mf, rr)                                                    \
    do {                                                                    \
        float ff = __int_as_float(mf);                                      \
        switch ((mx >> 24) & 3) {                                           \
        case 0: A0[0]=fmaf(ff,bf_lo(rr),A0[0]); A1[0]=fmaf(ff,bf_hi(rr),A1[0]); break; \
        case 1: A0[1]=fmaf(ff,bf_lo(rr),A0[1]); A1[1]=fmaf(ff,bf_hi(rr),A1[1]); break; \
        case 2: A0[2]=fmaf(ff,bf_lo(rr),A0[2]); A1[2]=fmaf(ff,bf_hi(rr),A1[2]); break; \
        default:A0[3]=fmaf(ff,bf_lo(rr),A0[3]); A1[3]=fmaf(ff,bf_hi(rr),A1[3]); break; \
        }                                                                   \
    } while (0)

__global__ __launch_bounds__(256) void layer_kernel(
        const unsigned short* __restrict__ cur,   // bf16 [N_PAD, DIM]
        const float* __restrict__ v,              // fp32 [N, DIM]
        const int2*  __restrict__ meta,
        const int*   __restrict__ goff,
        const uint4* __restrict__ wfrag,
        const float* __restrict__ bias,
        unsigned short* __restrict__ out_bf,
        float* __restrict__ out_f,
        int last) {
    __shared__ __align__(16) unsigned short xs[16 * 144];  // pad 144: 16B-aligned rows

    int tid  = threadIdx.x;
    int wv   = tid >> 6, lane = tid & 63;
    int g    = blockIdx.x * 4 + wv;

    float A0[4] = {0.f, 0.f, 0.f, 0.f};
    float A1[4] = {0.f, 0.f, 0.f, 0.f};

    int beg = __builtin_amdgcn_readfirstlane(goff[g]);
    int end = __builtin_amdgcn_readfirstlane(goff[g + 1]);
    const char* base = (const char*)cur + lane * 4;

    int c = beg;
    if ((c & 1) && c < end) {
        int2 m = meta[c];
        unsigned rr = *(const unsigned*)(base + (unsigned)(m.x & 0x00FFFFFF));
        GACC(m.x, m.y, rr);
        ++c;
    }
    for (; c + 8 <= end; c += 8) {
        int4 m0 = *(const int4*)(meta + c);
        int4 m1 = *(const int4*)(meta + c + 2);
        int4 m2 = *(const int4*)(meta + c + 4);
        int4 m3 = *(const int4*)(meta + c + 6);
        unsigned r0 = *(const unsigned*)(base + (unsigned)(m0.x & 0x00FFFFFF));
        unsigned r1 = *(const unsigned*)(base + (unsigned)(m0.z & 0x00FFFFFF));
        unsigned r2 = *(const unsigned*)(base + (unsigned)(m1.x & 0x00FFFFFF));
        unsigned r3 = *(const unsigned*)(base + (unsigned)(m1.z & 0x00FFFFFF));
        unsigned r4 = *(const unsigned*)(base + (unsigned)(m2.x & 0x00FFFFFF));
        unsigned r5 = *(const unsigned*)(base + (unsigned)(m2.z & 0x00FFFFFF));
        unsigned r6 = *(const unsigned*)(base + (unsigned)(m3.x & 0x00FFFFFF));
        unsigned r7 = *(const unsigned*)(base + (unsigned)(m3.z & 0x00FFFFFF));
        GACC(m0.x, m0.y, r0); GACC(m0.z, m0.w, r1);
        GACC(m1.x, m1.y, r2); GACC(m1.z, m1.w, r3);
        GACC(m2.x, m2.y, r4); GACC(m2.z, m2.w, r5);
        GACC(m3.x, m3.y, r6); GACC(m3.z, m3.w, r7);
    }
    for (; c < end; ++c) {
        int2 m = meta[c];
        unsigned rr = *(const unsigned*)(base + (unsigned)(m.x & 0x00FFFFFF));
        GACC(m.x, m.y, rr);
    }

    // epilogue of gather: add skip v, stage 16 rows in LDS as bf16
    int nbase = g * 4;
    #pragma unroll
    for (int t = 0; t < 4; ++t) {
        int n = nbase + t;
        float x0 = A0[t], x1 = A1[t];
        if (n < N_NODES) {
            float2 vv = *(const float2*)(v + (size_t)n * DIM + lane * 2);
            x0 += vv.x; x1 += vv.y;
        }
        unsigned o = (unsigned)f2bf(x0) | ((unsigned)f2bf(x1) << 16);
        *(unsigned*)&xs[(wv * 4 + t) * 144 + lane * 2] = o;
    }
    __syncthreads();

    // GEMM: 16 rows x 128 cols; wave wv owns col-tiles 2wv, 2wv+1
    int quad = lane >> 4, l16 = lane & 15;
    f32x4 acc0 = {0.f, 0.f, 0.f, 0.f}, acc1 = {0.f, 0.f, 0.f, 0.f};
    #pragma unroll
    for (int kk = 0; kk < 4; ++kk) {
        bf16x8 af = *(const bf16x8*)&xs[l16 * 144 + kk * 32 + quad * 8];
        uint4 w0 = wfrag[(kk * 8 + 2 * wv) * 64 + lane];
        uint4 w1 = wfrag[(kk * 8 + 2 * wv + 1) * 64 + lane];
        acc0 = __builtin_amdgcn_mfma_f32_16x16x32_bf16(af, __builtin_bit_cast(bf16x8, w0), acc0, 0, 0, 0);
        acc1 = __builtin_amdgcn_mfma_f32_16x16x32_bf16(af, __builtin_bit_cast(bf16x8, w1), acc1, 0, 0, 0);
    }

    int rbase = blockIdx.x * 16 + quad * 4;
    #pragma unroll
    for (int h = 0; h < 2; ++h) {
        int nt  = 2 * wv + h;
        int col = nt * 16 + l16;
        float b = bias[col];
        f32x4 a = h ? acc1 : acc0;
        #pragma unroll
        for (int r = 0; r < 4; ++r) {
            int orow = rbase + r;
            if (orow < N_NODES) {
                float val = fmaxf(a[r] + b, 0.f);
                if (last) out_f[(size_t)orow * DIM + col] = val;
                else      out_bf[(size_t)orow * DIM + col] = f2bf(val);
            }
        }
    }
}

// ---------------------------------------------------------------------------
extern "C" void kernel_launch(void* const* d_in, const int* in_sizes, int n_in,
                              void* d_out, int out_size, void* d_ws, size_t ws_size,
                              hipStream_t stream) {
    const float* v     = (const float*)d_in[0];
    const float* e     = (const float*)d_in[1];
    const int*   src   = (const int*)  d_in[2];
    const int*   dst   = (const int*)  d_in[3];
    const float* Aw    = (const float*)d_in[4];
    const float* Ab    = (const float*)d_in[5];
    const float* rs    = (const float*)d_in[6];
    const float* sigma = (const float*)d_in[7];
    float* out = (float*)d_out;

    // ---- workspace layout (~51.5 MB) ----
    char* p = (char*)d_ws;
    int2*           meta  = (int2*)p;            p += (size_t)N_EDGES * 8;       // 12.8 MB (final CSR)
    unsigned short* bufV  = (unsigned short*)p;  p += (size_t)N_PAD * DIM * 2;   // 12.81 MB
    unsigned short* bufA  = (unsigned short*)p;  p += (size_t)N_PAD * DIM * 2;   // 12.81 MB
    unsigned short* bufB  = (unsigned short*)p;  p += (size_t)N_PAD * DIM * 2;   // 12.81 MB
    uint4*          wfrag = (uint4*)p;           p += 2048 * 16;                 //  32 KB
    int*            gtot  = (int*)p;             p += (size_t)NG4 * 4;           //  50 KB
    int*            goff  = (int*)p;             p += (size_t)(NG4 + 1) * 4;     //  50 KB
    // aliases (NB_PRE*NG4*4 = 12,812,288 B = exactly one buf; dead before first layer write)
    int* partial = (int*)bufA;                   // dead after kbase
    int* pbase   = (int*)bufB;                   // dead after reorder

    prep_kernel<<<6258, 256, 0, stream>>>(v, bufV, Aw, wfrag);
    countp_kernel<<<NB_PRE, 256, 0, stream>>>(dst, partial);
    ktot_kernel<<<(NG4 + 255) / 256, 256, 0, stream>>>(partial, gtot);
    kscan_kernel<<<1, 256, 0, stream>>>(gtot, goff);
    kbase_kernel<<<(NG4 + 255) / 256, 256, 0, stream>>>(partial, goff, pbase);
    reorder_kernel<<<NB_PRE, 256, 0, stream>>>(e, src, dst, rs, sigma, pbase, meta);

    const int LB = NG4 / 4;   // 3128 blocks, 4 waves each = 16 nodes/block
    // L0: bufV -> bufA ; L1: bufA -> bufB ; L2: bufB -> out (fp32)
    layer_kernel<<<LB, 256, 0, stream>>>(bufV, v, meta, goff, wfrag, Ab, bufA, nullptr, 0);
    layer_kernel<<<LB, 256, 0, stream>>>(bufA, v, meta, goff, wfrag, Ab, bufB, nullptr, 0);
    layer_kernel<<<LB, 256, 0, stream>>>(bufB, v, meta, goff, wfrag, Ab, nullptr, out, 1);
}